// Round 6
// baseline (121.935 us; speedup 1.0000x reference)
//
#include <hip/hip_runtime.h>
#include <hip/hip_fp16.h>

#define P_PAD 208

typedef __attribute__((ext_vector_type(8))) short f16x8;
typedef __attribute__((ext_vector_type(4))) float f32x4;

__device__ __forceinline__ unsigned short f2h(float x) {
    __half h = __float2half(x);           // RNE f32 -> f16
    unsigned short u;
    __builtin_memcpy(&u, &h, 2);
    return u;
}

// ---------------- kernel 1: L2-normalize rows, f32 -> f16, pad to 208 rows ----
__global__ __launch_bounds__(256) void norm_kernel(
    const float* __restrict__ feats, const float* __restrict__ nfeats,
    unsigned short* __restrict__ fH, unsigned short* __restrict__ nfH,
    unsigned* __restrict__ scoresU)
{
    if (blockIdx.x == 0) {                 // zero the score-max accumulators (replay-safe)
        for (int i = threadIdx.x; i < 2048; i += 256) scoresU[i] = 0u;
    }
    int row  = blockIdx.x * 4 + (threadIdx.x >> 6);   // one wave per padded row
    int lane = threadIdx.x & 63;
    const int ROWS_F = 32 * P_PAD;
    const float* src;
    unsigned short* dst;
    int r;
    if (row < ROWS_F) {
        int a = row / P_PAD; r = row % P_PAD;
        src = feats + ((size_t)a * 196 + r) * 128;
        dst = fH + (size_t)row * 128;
    } else {
        int row2 = row - ROWS_F;
        int b = row2 / P_PAD; r = row2 % P_PAD;
        src = nfeats + ((size_t)b * 196 + r) * 128;
        dst = nfH + (size_t)row2 * 128;
    }
    if (r < 196) {
        float2 v = *(const float2*)(src + lane * 2);
        float ss = v.x * v.x + v.y * v.y;
        #pragma unroll
        for (int m = 1; m < 64; m <<= 1) ss += __shfl_xor(ss, m, 64);
        float rn = rsqrtf(ss);
        ushort2 o; o.x = f2h(v.x * rn); o.y = f2h(v.y * rn);
        *(ushort2*)(dst + lane * 2) = o;
    } else {
        *(unsigned int*)(dst + lane * 2) = 0u;   // zero pad rows
    }
}

// ---------------- kernel 2: half-A-panel in LDS, NMx NQ output grid per wave ----
// One q-group: NQ q-tiles of one b, K=128 accumulation with 2-deep B lookahead,
// max-fold into runmax. MASKED only for the final q-tile (q=192..207).
template <int NM, int NQ, bool MASKED>
__device__ __forceinline__ void qgroup(
    const unsigned short* __restrict__ nb, int qt0, const f16x8* __restrict__ Apanel,
    int lm0, int lm1, int lr, int lg, float (&runmax)[2][4])
{
    f32x4 acc[NM][NQ];
    #pragma unroll
    for (int m = 0; m < NM; ++m)
        #pragma unroll
        for (int n = 0; n < NQ; ++n) acc[m][n] = (f32x4){0.f, 0.f, 0.f, 0.f};

    f16x8 s0[NQ], s1[NQ];
    #pragma unroll
    for (int n = 0; n < NQ; ++n) s0[n] = *(const f16x8*)(nb + (size_t)(qt0 + n) * 2048);
    #pragma unroll
    for (int n = 0; n < NQ; ++n) s1[n] = *(const f16x8*)(nb + (size_t)(qt0 + n) * 2048 + 32);

    const int lm[2] = {lm0, lm1};
    #pragma unroll
    for (int ks = 0; ks < 4; ++ks) {
        f16x8* bc = (ks & 1) ? s1 : s0;       // constant after unroll
        f16x8 af[NM];
        #pragma unroll
        for (int m = 0; m < NM; ++m)
            af[m] = Apanel[((lm[m] * 16 + lr) << 4) | ((ks * 4 + lg) ^ (lr & 7))];
        #pragma unroll
        for (int m = 0; m < NM; ++m)
            #pragma unroll
            for (int n = 0; n < NQ; ++n)
                asm("v_mfma_f32_16x16x32_f16 %0, %1, %2, %0"
                    : "+v"(acc[m][n]) : "v"(af[m]), "v"(bc[n]));
        if (ks < 2) {                          // reload consumed set for ks+2 (2-deep)
            #pragma unroll
            for (int n = 0; n < NQ; ++n)
                bc[n] = *(const f16x8*)(nb + (size_t)(qt0 + n) * 2048 + (ks + 2) * 32);
        }
    }
    asm volatile("s_nop 7\n\ts_nop 7");        // MFMA -> VALU hazard insurance
    #pragma unroll
    for (int m = 0; m < NM; ++m)
        #pragma unroll
        for (int n = 0; n < NQ; ++n)
            #pragma unroll
            for (int r = 0; r < 4; ++r) {
                float v = acc[m][n][r];
                if (MASKED) v = (lr < 4) ? v : -3.0f;   // q=192+lr valid iff lr<4
                runmax[m][r] = fmaxf(runmax[m][r], v);
            }
}

__global__ __launch_bounds__(256, 4) void simmax_kernel(
    const unsigned short* __restrict__ fH, const unsigned short* __restrict__ nfH,
    const float* __restrict__ mask, float* __restrict__ sp, unsigned* __restrict__ scoresU)
{
    int blk = blockIdx.x;
    int a2 = blk & 63, bg = blk >> 6;     // 64 consecutive blocks share the 4 b-panels
    int a = a2 >> 1, half = a2 & 1;       // half 0: m-tiles 0..6; half 1: m-tiles 7..12
    int ntiles = half ? 6 : 7, row0 = half ? 112 : 0;
    int tid = threadIdx.x, wave = tid >> 6, lane = tid & 63;
    int lr = lane & 15, lg = lane >> 4;

    __shared__ f16x8 Apanel[1792];        // up to 112 rows x 16 chunks, chunk col ^= row&7

    const f16x8* fsrc = (const f16x8*)(fH + ((size_t)a * P_PAD + row0) * 128);
    int nch = ntiles * 256;
    for (int c = tid; c < nch; c += 256) {
        int row = c >> 4, cc = c & 15;
        Apanel[(row << 4) | (cc ^ (row & 7))] = fsrc[c];
    }
    __syncthreads();

    bool two = (wave + 4) < ntiles;       // waves owning a second m-tile
    int lm0 = wave, lm1 = wave + 4;

    for (int bi = 0; bi < 4; ++bi) {
        int b = bg * 4 + bi;
        const unsigned short* nb = nfH + (size_t)b * P_PAD * 128 + lr * 128 + lg * 8;

        float runmax[2][4];
        #pragma unroll
        for (int m = 0; m < 2; ++m)
            #pragma unroll
            for (int r = 0; r < 4; ++r) runmax[m][r] = -3.0f;

        if (two) {
            qgroup<2, 4, false>(nb, 0,  Apanel, lm0, lm1, lr, lg, runmax);
            qgroup<2, 4, false>(nb, 4,  Apanel, lm0, lm1, lr, lg, runmax);
            qgroup<2, 4, false>(nb, 8,  Apanel, lm0, lm1, lr, lg, runmax);
            qgroup<2, 1, true >(nb, 12, Apanel, lm0, lm1, lr, lg, runmax);
        } else {
            qgroup<1, 4, false>(nb, 0,  Apanel, lm0, lm1, lr, lg, runmax);
            qgroup<1, 4, false>(nb, 4,  Apanel, lm0, lm1, lr, lg, runmax);
            qgroup<1, 4, false>(nb, 8,  Apanel, lm0, lm1, lr, lg, runmax);
            qgroup<1, 1, true >(nb, 12, Apanel, lm0, lm1, lr, lg, runmax);
        }

        // reduce max across the 16 q-columns (lane bits 0..3), write sp, wave max
        float wmax = 0.0f;
        int nm = two ? 2 : 1;
        for (int m = 0; m < nm; ++m) {
            int gt = (half ? 7 : 0) + (m ? lm1 : lm0);   // global m-tile
            #pragma unroll
            for (int r = 0; r < 4; ++r) {
                float mx = runmax[m][r];
                mx = fmaxf(mx, __shfl_xor(mx, 1, 64));
                mx = fmaxf(mx, __shfl_xor(mx, 2, 64));
                mx = fmaxf(mx, __shfl_xor(mx, 4, 64));
                mx = fmaxf(mx, __shfl_xor(mx, 8, 64));
                if (lr == 0) {
                    int p = gt * 16 + lg * 4 + r;        // C/D: row = 4*(lane>>4)+reg
                    if (p < 196) {
                        float d = 0.5f * sqrtf(fmaxf(2.0f - 2.0f * mx, 0.0f)) * mask[a * 196 + p];
                        sp[((size_t)a * 196 + p) * 64 + b] = d;   // [a][p][b]
                        wmax = fmaxf(wmax, d);
                    }
                }
            }
        }
        wmax = fmaxf(wmax, __shfl_xor(wmax, 16, 64));
        wmax = fmaxf(wmax, __shfl_xor(wmax, 32, 64));
        if (lane == 0) atomicMax(&scoresU[a * 64 + b], __float_as_uint(wmax));  // d >= 0
    }
}

// ---------------- kernel 3: patch mean over b + scores mean ----
__global__ __launch_bounds__(256) void patchmean_kernel(
    const float* __restrict__ sp, const float* __restrict__ scores,
    float* __restrict__ patch, float* __restrict__ out)
{
    int a = blockIdx.x, tid = threadIdx.x;
    if (tid < 196) {
        const f32x4* v = (const f32x4*)(sp + ((size_t)a * 196 + tid) * 64);
        float s = 0.0f;
        #pragma unroll
        for (int j = 0; j < 16; ++j) { f32x4 x = v[j]; s += x[0] + x[1] + x[2] + x[3]; }
        patch[a * 196 + tid] = s * (1.0f / 64.0f);
    }
    if (tid >= 192 && tid < 256) {         // wave 3: scores mean
        int l = tid - 192;
        float s = scores[a * 64 + l];
        #pragma unroll
        for (int m = 1; m < 64; m <<= 1) s += __shfl_xor(s, m, 64);
        if (l == 0) out[a] = s * (1.0f / 64.0f);
    }
}

// ---------------- kernel 4: bilinear 14x14 -> 224x224, 8-row bands ----
__global__ __launch_bounds__(256) void upsample_kernel(
    const float* __restrict__ patch, float* __restrict__ out)
{
    int bid = blockIdx.x;
    int a = bid / 28, band = bid % 28;
    __shared__ float pt[196];
    if (threadIdx.x < 196) pt[threadIdx.x] = patch[a * 196 + threadIdx.x];
    __syncthreads();

    float* op = out + 32 + (size_t)a * 50176 + band * 8 * 224;
    for (int t = threadIdx.x; t < 8 * 224; t += 256) {
        int h = band * 8 + (t / 224), w = t % 224;
        float sh = fmaxf((h + 0.5f) * 0.0625f - 0.5f, 0.0f);   // 14/224 = 1/16
        float sw = fmaxf((w + 0.5f) * 0.0625f - 0.5f, 0.0f);
        int h0 = (int)sh, w0 = (int)sw;
        int h1 = min(h0 + 1, 13), w1 = min(w0 + 1, 13);
        float fh = sh - (float)h0, fw = sw - (float)w0;
        float v00 = pt[h0 * 14 + w0], v01 = pt[h0 * 14 + w1];
        float v10 = pt[h1 * 14 + w0], v11 = pt[h1 * 14 + w1];
        op[t] = (1.0f - fh) * ((1.0f - fw) * v00 + fw * v01)
              +         fh  * ((1.0f - fw) * v10 + fw * v11);
    }
}

extern "C" void kernel_launch(void* const* d_in, const int* in_sizes, int n_in,
                              void* d_out, int out_size, void* d_ws, size_t ws_size,
                              hipStream_t stream) {
    const float* feats  = (const float*)d_in[0];   // [32,196,128]
    const float* nfeats = (const float*)d_in[1];   // [64,196,128]
    const float* mask   = (const float*)d_in[2];   // [32,196]
    float* out = (float*)d_out;                    // 32 + 32*224*224

    char* w = (char*)d_ws;
    unsigned short* fH  = (unsigned short*)(w);            // 32*208*128 f16 = 1,703,936 B
    unsigned short* nfH = (unsigned short*)(w + 1703936);  // 64*208*128 f16 = 3,407,872 B
    float* sp     = (float*)(w + 5111808);                 // 32*196*64 f32  = 1,605,632 B
    float* scores = (float*)(w + 6717440);                 // 2048 f32
    float* patch  = (float*)(w + 6725632);                 // 32*196 f32

    norm_kernel<<<4992, 256, 0, stream>>>(feats, nfeats, fH, nfH, (unsigned*)scores);
    simmax_kernel<<<1024, 256, 0, stream>>>(fH, nfH, mask, sp, (unsigned*)scores);
    patchmean_kernel<<<32, 256, 0, stream>>>(sp, scores, patch, out);
    upsample_kernel<<<896, 256, 0, stream>>>(patch, out);
}

// Round 7
// 84.325 us; speedup vs baseline: 1.4460x; 1.4460x over previous
//
#include <hip/hip_runtime.h>
#include <hip/hip_fp16.h>

#define P_PAD 208

typedef __attribute__((ext_vector_type(8))) short f16x8;
typedef __attribute__((ext_vector_type(4))) float f32x4;

__device__ __forceinline__ unsigned short f2h(float x) {
    __half h = __float2half(x);           // RNE f32 -> f16
    unsigned short u;
    __builtin_memcpy(&u, &h, 2);
    return u;
}

// async global->LDS, 16B per lane. LDS dest is wave-uniform base + lane*16.
__device__ __forceinline__ void gll16(const void* g, void* l) {
    __builtin_amdgcn_global_load_lds(
        (const __attribute__((address_space(1))) unsigned*)g,
        (__attribute__((address_space(3))) unsigned*)l, 16, 0, 0);
}

// ---------------- kernel 1: L2-normalize rows, f32 -> f16, pad to 208 rows ----
__global__ __launch_bounds__(256) void norm_kernel(
    const float* __restrict__ feats, const float* __restrict__ nfeats,
    unsigned short* __restrict__ fH, unsigned short* __restrict__ nfH,
    unsigned* __restrict__ scoresU)
{
    if (blockIdx.x == 0) {                 // zero score-max accumulators (replay-safe)
        for (int i = threadIdx.x; i < 2048; i += 256) scoresU[i] = 0u;
    }
    int row  = blockIdx.x * 4 + (threadIdx.x >> 6);   // one wave per padded row
    int lane = threadIdx.x & 63;
    const int ROWS_F = 32 * P_PAD;
    const float* src;
    unsigned short* dst;
    int r;
    if (row < ROWS_F) {
        int a = row / P_PAD; r = row % P_PAD;
        src = feats + ((size_t)a * 196 + r) * 128;
        dst = fH + (size_t)row * 128;
    } else {
        int row2 = row - ROWS_F;
        int b = row2 / P_PAD; r = row2 % P_PAD;
        src = nfeats + ((size_t)b * 196 + r) * 128;
        dst = nfH + (size_t)row2 * 128;
    }
    if (r < 196) {
        float2 v = *(const float2*)(src + lane * 2);
        float ss = v.x * v.x + v.y * v.y;
        #pragma unroll
        for (int m = 1; m < 64; m <<= 1) ss += __shfl_xor(ss, m, 64);
        float rn = rsqrtf(ss);
        ushort2 o; o.x = f2h(v.x * rn); o.y = f2h(v.y * rn);
        *(ushort2*)(dst + lane * 2) = o;
    } else {
        *(unsigned int*)(dst + lane * 2) = 0u;   // zero pad rows
    }
}

// ---------------- kernel 2: LDS-resident panels, global_load_lds staged ----
// Stage one 208x128 f16 panel (3328 16B-chunks) into LDS, source-side swizzled:
// LDS slot (row, cc) holds global chunk (row, cc ^ (row&7)). 13 issues/thread.
__device__ __forceinline__ void stage_panel(const f16x8* __restrict__ g, f16x8* l, int tid) {
    int wave = tid >> 6;
    #pragma unroll
    for (int i = 0; i < 13; ++i) {
        int slot = i * 256 + tid;
        int row = slot >> 4, cc = slot & 15;
        gll16(g + row * 16 + (cc ^ (row & 7)), l + i * 256 + wave * 64);
    }
}

// Compute NM m-rows x all 13 q-tiles of one b from LDS, fold max over q,
// write sp + fold wave max. acc defined by inline asm (cannot be remat'd).
template <int NM>
__device__ __forceinline__ void mrows(
    const f16x8* __restrict__ Al, const f16x8* __restrict__ Bl,
    int mr0, int lr, int lg, int a, int b,
    const float* __restrict__ mask, float* __restrict__ sp, float& wmax)
{
    f32x4 acc[NM][13];
    #pragma unroll
    for (int m = 0; m < NM; ++m)
        #pragma unroll
        for (int n = 0; n < 13; ++n) acc[m][n] = (f32x4){0.f, 0.f, 0.f, 0.f};

    int sw = lr & 7;
    #pragma unroll
    for (int ks = 0; ks < 4; ++ks) {
        int c = (ks * 4 + lg) ^ sw;              // swizzled chunk column
        f16x8 bf[13];
        #pragma unroll
        for (int n = 0; n < 13; ++n) bf[n] = Bl[((n * 16 + lr) << 4) + c];
        f16x8 af[NM];
        #pragma unroll
        for (int m = 0; m < NM; ++m) af[m] = Al[(((mr0 + m) * 16 + lr) << 4) + c];
        #pragma unroll
        for (int m = 0; m < NM; ++m)
            #pragma unroll
            for (int n = 0; n < 13; ++n)
                asm("v_mfma_f32_16x16x32_f16 %0, %1, %2, %0"
                    : "+v"(acc[m][n]) : "v"(af[m]), "v"(bf[n]));
    }
    asm volatile("s_nop 7\n\ts_nop 7");          // MFMA -> VALU hazard insurance

    #pragma unroll
    for (int m = 0; m < NM; ++m) {
        #pragma unroll
        for (int r = 0; r < 4; ++r) {
            float mx = acc[m][0][r];
            #pragma unroll
            for (int n = 1; n < 12; ++n) mx = fmaxf(mx, acc[m][n][r]);
            float v12 = (lr < 4) ? acc[m][12][r] : -3.0f;   // q=192+lr valid iff lr<4
            mx = fmaxf(mx, v12);
            mx = fmaxf(mx, __shfl_xor(mx, 1, 64));
            mx = fmaxf(mx, __shfl_xor(mx, 2, 64));
            mx = fmaxf(mx, __shfl_xor(mx, 4, 64));
            mx = fmaxf(mx, __shfl_xor(mx, 8, 64));
            if (lr == 0) {
                int p = (mr0 + m) * 16 + lg * 4 + r;        // C/D: row = 4*(lane>>4)+reg
                if (p < 196) {
                    float d = 0.5f * sqrtf(fmaxf(2.0f - 2.0f * mx, 0.0f)) * mask[a * 196 + p];
                    sp[((size_t)a * 196 + p) * 64 + b] = d;  // [a][p][b]
                    wmax = fmaxf(wmax, d);
                }
            }
        }
    }
}

__global__ __launch_bounds__(256, 1) void simmax_kernel(
    const unsigned short* __restrict__ fH, const unsigned short* __restrict__ nfH,
    const float* __restrict__ mask, float* __restrict__ sp, unsigned* __restrict__ scoresU)
{
    __shared__ f16x8 lds[3 * 3328];       // A | B0 | B1 = 159744 B
    f16x8* Al = lds;
    f16x8* B0 = lds + 3328;
    f16x8* B1 = lds + 6656;

    int blk = blockIdx.x;
    int a = blk & 31, bg = blk >> 5;      // 256 blocks = 32 a x 8 b-groups, 1/CU
    int b0 = bg * 8;
    int tid = threadIdx.x, wave = tid >> 6, lane = tid & 63;
    int lr = lane & 15, lg = lane >> 4;

    stage_panel((const f16x8*)(fH  + (size_t)a  * P_PAD * 128), Al, tid);
    stage_panel((const f16x8*)(nfH + (size_t)b0 * P_PAD * 128), B0, tid);
    __syncthreads();                      // vmcnt(0) drain: A + B0 ready

    for (int bi = 0; bi < 8; ++bi) {
        f16x8* Bcur = (bi & 1) ? B1 : B0;
        f16x8* Bnxt = (bi & 1) ? B0 : B1;
        if (bi < 7)                       // async: lands during this bi's compute
            stage_panel((const f16x8*)(nfH + (size_t)(b0 + bi + 1) * P_PAD * 128), Bnxt, tid);

        int b = b0 + bi;
        float wmax = 0.0f;
        switch (wave) {                   // rows: w0:0-3  w1:4-6  w2:7-9  w3:10-12
            case 0: mrows<2>(Al, Bcur, 0,  lr, lg, a, b, mask, sp, wmax);
                    mrows<2>(Al, Bcur, 2,  lr, lg, a, b, mask, sp, wmax); break;
            case 1: mrows<2>(Al, Bcur, 4,  lr, lg, a, b, mask, sp, wmax);
                    mrows<1>(Al, Bcur, 6,  lr, lg, a, b, mask, sp, wmax); break;
            case 2: mrows<2>(Al, Bcur, 7,  lr, lg, a, b, mask, sp, wmax);
                    mrows<1>(Al, Bcur, 9,  lr, lg, a, b, mask, sp, wmax); break;
            default: mrows<2>(Al, Bcur, 10, lr, lg, a, b, mask, sp, wmax);
                     mrows<1>(Al, Bcur, 12, lr, lg, a, b, mask, sp, wmax); break;
        }
        // wave max -> global atomic (uint order == float order for d >= 0)
        wmax = fmaxf(wmax, __shfl_xor(wmax, 16, 64));
        wmax = fmaxf(wmax, __shfl_xor(wmax, 32, 64));
        if (lane == 0) atomicMax(&scoresU[a * 64 + b], __float_as_uint(wmax));

        __syncthreads();                  // all waves done with Bcur; Bnxt drained
    }
}

// ---------------- kernel 3: patch mean over b + scores mean ----
__global__ __launch_bounds__(256) void patchmean_kernel(
    const float* __restrict__ sp, const float* __restrict__ scores,
    float* __restrict__ patch, float* __restrict__ out)
{
    int a = blockIdx.x, tid = threadIdx.x;
    if (tid < 196) {
        const f32x4* v = (const f32x4*)(sp + ((size_t)a * 196 + tid) * 64);
        float s = 0.0f;
        #pragma unroll
        for (int j = 0; j < 16; ++j) { f32x4 x = v[j]; s += x[0] + x[1] + x[2] + x[3]; }
        patch[a * 196 + tid] = s * (1.0f / 64.0f);
    }
    if (tid >= 192 && tid < 256) {         // wave 3: scores mean
        int l = tid - 192;
        float s = scores[a * 64 + l];
        #pragma unroll
        for (int m = 1; m < 64; m <<= 1) s += __shfl_xor(s, m, 64);
        if (l == 0) out[a] = s * (1.0f / 64.0f);
    }
}

// ---------------- kernel 4: bilinear 14x14 -> 224x224, 8-row bands ----
__global__ __launch_bounds__(256) void upsample_kernel(
    const float* __restrict__ patch, float* __restrict__ out)
{
    int bid = blockIdx.x;
    int a = bid / 28, band = bid % 28;
    __shared__ float pt[196];
    if (threadIdx.x < 196) pt[threadIdx.x] = patch[a * 196 + threadIdx.x];
    __syncthreads();

    float* op = out + 32 + (size_t)a * 50176 + band * 8 * 224;
    for (int t = threadIdx.x; t < 8 * 224; t += 256) {
        int h = band * 8 + (t / 224), w = t % 224;
        float sh = fmaxf((h + 0.5f) * 0.0625f - 0.5f, 0.0f);   // 14/224 = 1/16
        float sw = fmaxf((w + 0.5f) * 0.0625f - 0.5f, 0.0f);
        int h0 = (int)sh, w0 = (int)sw;
        int h1 = min(h0 + 1, 13), w1 = min(w0 + 1, 13);
        float fh = sh - (float)h0, fw = sw - (float)w0;
        float v00 = pt[h0 * 14 + w0], v01 = pt[h0 * 14 + w1];
        float v10 = pt[h1 * 14 + w0], v11 = pt[h1 * 14 + w1];
        op[t] = (1.0f - fh) * ((1.0f - fw) * v00 + fw * v01)
              +         fh  * ((1.0f - fw) * v10 + fw * v11);
    }
}

extern "C" void kernel_launch(void* const* d_in, const int* in_sizes, int n_in,
                              void* d_out, int out_size, void* d_ws, size_t ws_size,
                              hipStream_t stream) {
    const float* feats  = (const float*)d_in[0];   // [32,196,128]
    const float* nfeats = (const float*)d_in[1];   // [64,196,128]
    const float* mask   = (const float*)d_in[2];   // [32,196]
    float* out = (float*)d_out;                    // 32 + 32*224*224

    char* w = (char*)d_ws;
    unsigned short* fH  = (unsigned short*)(w);            // 32*208*128 f16 = 1,703,936 B
    unsigned short* nfH = (unsigned short*)(w + 1703936);  // 64*208*128 f16 = 3,407,872 B
    float* sp     = (float*)(w + 5111808);                 // 32*196*64 f32  = 1,605,632 B
    float* scores = (float*)(w + 6717440);                 // 2048 f32
    float* patch  = (float*)(w + 6725632);                 // 32*196 f32

    norm_kernel<<<4992, 256, 0, stream>>>(feats, nfeats, fH, nfH, (unsigned*)scores);
    simmax_kernel<<<256, 256, 0, stream>>>(fH, nfH, mask, sp, (unsigned*)scores);
    patchmean_kernel<<<32, 256, 0, stream>>>(sp, scores, patch, out);
    upsample_kernel<<<896, 256, 0, stream>>>(patch, out);
}